// Round 5
// baseline (827.891 us; speedup 1.0000x reference)
//
#include <hip/hip_runtime.h>
#include <hip/hip_bf16.h>

// SNN forward: conv1(3->64,3x3,p1) -> IF -> pool2 -> conv2(64->64) -> IF -> pool2
//              -> fc1(16384->4096) -> IF -> fc2(4096->10) -> IF -> mean over T
// T=8 N=32 IMG=64.
// conv2 and fc1 use bf16 MFMA: spikes are exactly 0/1 (exact in bf16); fp32
// weights are 3-way bf16 split (hi+mid+lo) -> three MFMAs into one fp32
// accumulator == fp32 dot product to within fp32 rounding noise.
// fc1 R5: staging thread-map swapped (orow=t&15) -> Bs stores hit all 32 banks
// (was 8-way conflict, SQ_LDS_BANK_CONFLICT 2.2e7); 16-way K-split -> 1024
// blocks = 4/CU for wave-level staging/MFMA overlap.

#define T_STEPS 8
#define NB      32
#define CMID    64

typedef __bf16 bf16x2 __attribute__((ext_vector_type(2)));
typedef __bf16 bf16x4 __attribute__((ext_vector_type(4)));
typedef __bf16 bf16x8 __attribute__((ext_vector_type(8)));
typedef short  s16x8  __attribute__((ext_vector_type(8)));
typedef float  f32x4  __attribute__((ext_vector_type(4)));

struct Split3 { float h, m, l; };
__device__ __forceinline__ Split3 split3(float x) {
    Split3 s;
    __bf16 h = (__bf16)x;
    float r1 = x - (float)h;
    __bf16 m = (__bf16)r1;
    float r2 = r1 - (float)m;
    __bf16 l = (__bf16)r2;
    s.h = (float)h; s.m = (float)m; s.l = (float)l;
    return s;
}

// ------------------------------------------------- w2 -> 3-way-split frag order
__global__ void k_w2s(const float* __restrict__ w2, __bf16* __restrict__ w2s) {
    int idx = blockIdx.x * 256 + threadIdx.x;   // 36864 total
    int j    = idx & 7;
    int lane = (idx >> 3) & 63;
    int oh   = (idx >> 9) & 1;
    int kh   = (idx >> 10) & 1;
    int g    = idx >> 11;          // ch*9 + tap, 0..17
    int tap  = g % 9;
    int ch   = g / 9;
    int co = ch * 32 + oh * 16 + (lane & 15);
    int ci = kh * 32 + (lane >> 4) * 8 + j;
    float w = w2[co * 576 + ci * 9 + tap];
    Split3 s = split3(w);
    __bf16* o = w2s + (((size_t)(g * 2 + kh) * 2 + oh) * 3) * 512 + lane * 8 + j;
    o[0]    = (__bf16)s.h;
    o[512]  = (__bf16)s.m;
    o[1024] = (__bf16)s.l;
}

// ------------------------------------------ conv1 + IF + maxpool -> NHWC bf16
__global__ __launch_bounds__(256) void k_conv1_if_pool(
        const float* __restrict__ x, const float* __restrict__ w1,
        __bf16* __restrict__ spk1p) {
    int b   = blockIdx.x;               // 1024 = 32n * 8cog * 4pht
    int n   = b >> 5;
    int cog = (b >> 2) & 7;
    int pht = b & 3;
    int tid = threadIdx.x;
    int pw  = tid & 31;
    int ph  = pht * 8 + (tid >> 5);
    int ih0 = 2 * ph - 1, iw0 = 2 * pw - 1;

    float v[8][4];
#pragma unroll
    for (int a = 0; a < 8; a++)
#pragma unroll
        for (int p = 0; p < 4; p++) v[a][p] = 0.f;

    for (int t = 0; t < T_STEPS; t++) {
        const float* xb = x + (size_t)(t * NB + n) * 3 * 4096;
        float patch[3][4][4];
#pragma unroll
        for (int ci = 0; ci < 3; ci++)
#pragma unroll
            for (int dy = 0; dy < 4; dy++) {
                int ih = ih0 + dy;
                bool rok = ((unsigned)ih < 64u);
#pragma unroll
                for (int dx = 0; dx < 4; dx++) {
                    int iw = iw0 + dx;
                    patch[ci][dy][dx] = (rok && ((unsigned)iw < 64u))
                                            ? xb[ci * 4096 + ih * 64 + iw] : 0.f;
                }
            }
        bf16x8 sv;
#pragma unroll
        for (int c8 = 0; c8 < 8; c8++) {
            int co = cog * 8 + c8;
            const float* wc = w1 + co * 27;   // wave-uniform -> s_load
            float a0 = 0.f, a1 = 0.f, a2 = 0.f, a3 = 0.f;
#pragma unroll
            for (int ci = 0; ci < 3; ci++)
#pragma unroll
                for (int ky = 0; ky < 3; ky++)
#pragma unroll
                    for (int kx = 0; kx < 3; kx++) {
                        float w = wc[ci * 9 + ky * 3 + kx];
                        a0 += w * patch[ci][ky][kx];
                        a1 += w * patch[ci][ky][kx + 1];
                        a2 += w * patch[ci][ky + 1][kx];
                        a3 += w * patch[ci][ky + 1][kx + 1];
                    }
            float s0, s1, s2, s3;
            v[c8][0] += a0; s0 = (v[c8][0] >= 1.f) ? 1.f : 0.f; if (s0 > 0.f) v[c8][0] = 0.f;
            v[c8][1] += a1; s1 = (v[c8][1] >= 1.f) ? 1.f : 0.f; if (s1 > 0.f) v[c8][1] = 0.f;
            v[c8][2] += a2; s2 = (v[c8][2] >= 1.f) ? 1.f : 0.f; if (s2 > 0.f) v[c8][2] = 0.f;
            v[c8][3] += a3; s3 = (v[c8][3] >= 1.f) ? 1.f : 0.f; if (s3 > 0.f) v[c8][3] = 0.f;
            sv[c8] = (__bf16)fmaxf(fmaxf(s0, s1), fmaxf(s2, s3));
        }
        *(bf16x8*)(spk1p + ((size_t)(t * NB + n) * 1024 + ph * 32 + pw) * 64
                         + cog * 8) = sv;
    }
}

// -------------------------------- conv2 (MFMA) + IF + maxpool fused, t in-kernel
__global__ __launch_bounds__(256, 1) void k_conv2_if_pool(
        const short* __restrict__ spk1p,   // [256][32][32][64] bf16 bits
        const short* __restrict__ w2s,     // [2][55296] bf16 bits (frag order)
        __bf16* __restrict__ spk2) {       // [256][64][16][16]
    int b     = blockIdx.x;                // 512 = 32n * 8strip * 2ch
    int ch    = b & 1;
    int strip = (b >> 1) & 7;
    int n     = b >> 4;
    int tid   = threadIdx.x;
    int lane  = tid & 63;
    int wv    = tid >> 6;
    int mh    = wv >> 1, oh = wv & 1;
    int lm    = lane & 15, kq = lane >> 4;

    __shared__ short Bs[55296];            // 108 KB
    {
        const uint4* src = (const uint4*)(w2s + (size_t)ch * 55296);
        uint4* dst = (uint4*)Bs;
        for (int i = tid; i < 6912; i += 256) dst[i] = src[i];
    }
    __syncthreads();
    const short* Bsw = Bs + oh * 1536;

    f32x4 v[4];
#pragma unroll
    for (int i = 0; i < 4; i++) v[i] = (f32x4){0.f, 0.f, 0.f, 0.f};

    int co = ch * 32 + oh * 16 + lm;
    int pH = strip * 2 + mh;
    int h0 = strip * 4 + 2 * mh - 1;

#pragma unroll 1
    for (int t = 0; t < T_STEPS; t++) {
        const short* At = spk1p + (size_t)(t * NB + n) * 65536 + kq * 8;
        f32x4 acc[4];
#pragma unroll
        for (int i = 0; i < 4; i++) acc[i] = (f32x4){0.f, 0.f, 0.f, 0.f};

#pragma unroll 1
        for (int dy = 0; dy < 3; dy++) {
#pragma unroll 1
            for (int dx = 0; dx < 3; dx++) {
                const short* bp = Bsw + (dy * 3 + dx) * 6144 + lane * 8;
                s16x8 bf[2][3];
#pragma unroll
                for (int kh = 0; kh < 2; kh++)
#pragma unroll
                    for (int sp = 0; sp < 3; sp++)
                        bf[kh][sp] = *(const s16x8*)(bp + kh * 3072 + sp * 512);
#pragma unroll
                for (int i = 0; i < 4; i++) {
                    int hh = h0 + (i >> 1) + dy;
                    int ww = (i & 1) * 16 + lm + dx - 1;
                    bool ok = ((unsigned)hh < 32u) && ((unsigned)ww < 32u);
                    s16x8 a0 = {0, 0, 0, 0, 0, 0, 0, 0};
                    s16x8 a1 = {0, 0, 0, 0, 0, 0, 0, 0};
                    if (ok) {
                        const short* ap = At + (hh * 32 + ww) * 64;
                        a0 = *(const s16x8*)ap;
                        a1 = *(const s16x8*)(ap + 32);
                    }
#pragma unroll
                    for (int sp = 0; sp < 3; sp++) {
                        acc[i] = __builtin_amdgcn_mfma_f32_16x16x32_bf16(
                            a0, bf[0][sp], acc[i], 0, 0, 0);
                        acc[i] = __builtin_amdgcn_mfma_f32_16x16x32_bf16(
                            a1, bf[1][sp], acc[i], 0, 0, 0);
                    }
                }
            }
        }
        float s[4][4];
#pragma unroll
        for (int i = 0; i < 4; i++)
#pragma unroll
            for (int r = 0; r < 4; r++) {
                float vv = v[i][r] + acc[i][r];
                float sp = (vv >= 1.f) ? 1.f : 0.f;
                s[i][r] = sp;
                v[i][r] = (sp > 0.f) ? 0.f : vv;
            }
        __bf16* op = spk2 + ((size_t)(t * NB + n) * 64 + co) * 256 + pH * 16
                   + kq * 2;
#pragma unroll
        for (int i2 = 0; i2 < 2; i2++) {
            float p0 = fmaxf(fmaxf(s[i2][0], s[i2][1]),
                             fmaxf(s[i2 + 2][0], s[i2 + 2][1]));
            float p1 = fmaxf(fmaxf(s[i2][2], s[i2][3]),
                             fmaxf(s[i2 + 2][2], s[i2 + 2][3]));
            bf16x2 pv = {(__bf16)p0, (__bf16)p1};
            *(bf16x2*)(op + i2 * 8) = pv;
        }
    }
}

// ----------------------------------------------------------- fc1 via bf16 MFMA
// C[256 x 4096] = A[256 x 16384] * W^T.  Grid 1024 = 64 o-tiles x 16 ksplit.
// Block: 256 thr (4 waves), tile M=256 x O=64, K-chunk 1024 in k-iters of 64.
// Staging map: orow = t&15 -> wave's 64 b64-stores cover all 32 banks evenly
// (conflict-free); reads are lane*16 contiguous (conflict-free).
__global__ __launch_bounds__(256) void k_fc1_mfma(
        const short* __restrict__ A,      // spk2 bf16 bits [256][16384]
        const float* __restrict__ W,      // fc1 [4096][16384]
        float* __restrict__ part) {       // [16][256][4096]
    int b  = blockIdx.x;
    int nt = b & 63;
    int ks = b >> 6;
    int o0 = nt * 64;
    int kbase = ks * 1024;

    __shared__ __bf16 Bs[3][2][4][64][8];   // 24 KB

    int t    = threadIdx.x;
    int lane = t & 63;
    int wv_i = t >> 6;
    int mh   = wv_i >> 1;
    int oh   = wv_i & 1;

    // staging coords: thread t loads W row (o0+orow+16j), float4 at k4
    int orow = t & 15;                      // row within 16-group
    int kq   = t >> 4;                      // 0..15
    int k4   = kq * 4;                      // 0..60
    int sS   = kq >> 3;                     // k-half
    int kg   = (kq >> 1) & 3;               // lane quad
    int ke   = (kq & 1) * 4;                // element offset 0/4
    int ln   = orow + kg * 16;              // fragment lane index
    const float* wp0 = W + (size_t)(o0 + orow) * 16384 + kbase + k4;

    const short* ap0 = A + (size_t)(mh * 128 + (lane & 15)) * 16384
                         + kbase + ((lane >> 4) & 3) * 8;

    f32x4 acc[8][2];
#pragma unroll
    for (int i = 0; i < 8; i++)
#pragma unroll
        for (int oi = 0; oi < 2; oi++) acc[i][oi] = (f32x4){0.f, 0.f, 0.f, 0.f};

    float4 wv[4];
#pragma unroll
    for (int j = 0; j < 4; j++) wv[j] = *(const float4*)(wp0 + (size_t)j * 262144);

    for (int it = 0; it < 16; ++it) {
        __syncthreads();                    // prev iter's Bs reads done
#pragma unroll
        for (int j = 0; j < 4; j++) {
            float4 v4 = wv[j];
            Split3 sx = split3(v4.x), sy = split3(v4.y),
                   sz = split3(v4.z), sw = split3(v4.w);
            bf16x4 h4 = {(__bf16)sx.h, (__bf16)sy.h, (__bf16)sz.h, (__bf16)sw.h};
            bf16x4 m4 = {(__bf16)sx.m, (__bf16)sy.m, (__bf16)sz.m, (__bf16)sw.m};
            bf16x4 l4 = {(__bf16)sx.l, (__bf16)sy.l, (__bf16)sz.l, (__bf16)sw.l};
            *(bf16x4*)&Bs[0][sS][j][ln][ke] = h4;
            *(bf16x4*)&Bs[1][sS][j][ln][ke] = m4;
            *(bf16x4*)&Bs[2][sS][j][ln][ke] = l4;
        }
        __syncthreads();                    // Bs ready
        if (it < 15) {
#pragma unroll
            for (int j = 0; j < 4; j++)     // prefetch next B tile (overlaps MFMA)
                wv[j] = *(const float4*)(wp0 + (size_t)j * 262144 + (it + 1) * 64);
        }
        const short* ait = ap0 + it * 64;
#pragma unroll
        for (int s = 0; s < 2; ++s) {
            s16x8 bb[2][3];
#pragma unroll
            for (int oi = 0; oi < 2; oi++)
#pragma unroll
                for (int sp = 0; sp < 3; sp++)
                    bb[oi][sp] = *(const s16x8*)&Bs[sp][s][2 * oh + oi][lane][0];
            s16x8 av[8];
#pragma unroll
            for (int i = 0; i < 8; i++)
                av[i] = *(const s16x8*)(ait + s * 32 + (size_t)i * 16 * 16384);
#pragma unroll
            for (int i = 0; i < 8; i++)
#pragma unroll
                for (int oi = 0; oi < 2; oi++) {
                    acc[i][oi] = __builtin_amdgcn_mfma_f32_16x16x32_bf16(
                        av[i], bb[oi][0], acc[i][oi], 0, 0, 0);
                    acc[i][oi] = __builtin_amdgcn_mfma_f32_16x16x32_bf16(
                        av[i], bb[oi][1], acc[i][oi], 0, 0, 0);
                    acc[i][oi] = __builtin_amdgcn_mfma_f32_16x16x32_bf16(
                        av[i], bb[oi][2], acc[i][oi], 0, 0, 0);
                }
        }
    }
    int col = lane & 15;
    int rq  = (lane >> 4) * 4;
#pragma unroll
    for (int i = 0; i < 8; i++)
#pragma unroll
        for (int oi = 0; oi < 2; oi++)
#pragma unroll
            for (int r = 0; r < 4; r++) {
                int m = mh * 128 + i * 16 + rq + r;
                int o = o0 + (2 * oh + oi) * 16 + col;
                part[((size_t)ks * 256 + m) * 4096 + o] = acc[i][oi][r];
            }
}

// ----------------------------------------------- K-split reduce + IF for fc1
__global__ void k_fc1_if(const float* __restrict__ part,
                         float* __restrict__ spk3) {
    int idx = blockIdx.x * 256 + threadIdx.x;   // 131072
    int o = idx & 4095;
    int n = idx >> 12;
    float v = 0.f;
    for (int t = 0; t < T_STEPS; t++) {
        int m = t * NB + n;
        float s = 0.f;
#pragma unroll
        for (int ks = 0; ks < 16; ks++)
            s += part[((size_t)ks * 256 + m) * 4096 + o];
        v += s;
        float sp = (v >= 1.f) ? 1.f : 0.f;
        if (sp > 0.f) v = 0.f;
        spk3[(size_t)m * 4096 + o] = sp;
    }
}

// ------------------------------------------------------ fc2 + IF + time-mean
__global__ __launch_bounds__(256) void k_fc2_if_mean(
        const float* __restrict__ spk3, const float* __restrict__ fc2,
        float* __restrict__ out) {
    int b = blockIdx.x;                  // 320 = 32n * 10o
    int n = b / 10, o = b % 10;
    const float* wr = fc2 + o * 4096;
    __shared__ float red[256];
    int tid = threadIdx.x;
    float v = 0.f, cnt = 0.f;
    for (int t = 0; t < T_STEPS; t++) {
        const float* row = spk3 + (size_t)(t * NB + n) * 4096;
        float p = 0.f;
        for (int i = tid; i < 4096; i += 256) p += row[i] * wr[i];
        red[tid] = p;
        __syncthreads();
        for (int s = 128; s > 0; s >>= 1) {
            if (tid < s) red[tid] += red[tid + s];
            __syncthreads();
        }
        if (tid == 0) {
            v += red[0];
            float sp = (v >= 1.f) ? 1.f : 0.f;
            cnt += sp;
            if (sp > 0.f) v = 0.f;
        }
        __syncthreads();
    }
    if (tid == 0) out[n * 10 + o] = cnt * 0.125f;
}

// ---------------------------------------------------------------------- launch
extern "C" void kernel_launch(void* const* d_in, const int* in_sizes, int n_in,
                              void* d_out, int out_size, void* d_ws, size_t ws_size,
                              hipStream_t stream) {
    const float* x   = (const float*)d_in[0];   // [8,32,3,64,64]
    const float* w1  = (const float*)d_in[1];   // [64,3,3,3]
    const float* w2  = (const float*)d_in[2];   // [64,64,3,3]
    const float* fc1 = (const float*)d_in[3];   // [4096,16384]
    const float* fc2 = (const float*)d_in[4];   // [10,4096]
    float* out = (float*)d_out;                 // [32,10]

    float* ws = (float*)d_ws;
    // workspace layout (float slots)
    const size_t off_w2s   = 0;                          // 57344
    const size_t off_spk1p = 57344;                      // 8388608
    const size_t off_spk2  = off_spk1p + 8388608;        // 2097152
    const size_t off_part  = off_spk2 + 2097152;         // 16777216 (16 ksplits)
    const size_t off_spk3  = off_part + 16777216;        // 1048576
    __bf16* w2s   = (__bf16*)(ws + off_w2s);
    __bf16* spk1p = (__bf16*)(ws + off_spk1p);
    __bf16* spk2  = (__bf16*)(ws + off_spk2);
    float*  part  = ws + off_part;
    float*  spk3  = ws + off_spk3;

    k_w2s<<<144, 256, 0, stream>>>(w2, w2s);
    k_conv1_if_pool<<<1024, 256, 0, stream>>>(x, w1, spk1p);
    k_conv2_if_pool<<<512, 256, 0, stream>>>((const short*)spk1p,
                                             (const short*)w2s, spk2);
    k_fc1_mfma<<<1024, 256, 0, stream>>>((const short*)spk2, fc1, part);
    k_fc1_if<<<512, 256, 0, stream>>>(part, spk3);
    k_fc2_if_mean<<<320, 256, 0, stream>>>(spk3, fc2, out);
}